// Round 5
// baseline (1350.236 us; speedup 1.0000x reference)
//
#include <hip/hip_runtime.h>
#include <math.h>

#define B 16
#define N 32
#define M 64
#define D 512
#define NM (N * M)          // 2048
#define NBQ (B * NM)        // 32768
#define NUM_NEGS 32
#define SMOOTHING 0.1f
#define TD0 (1.0f - SMOOTHING)                    // 0.9
#define TDN (SMOOTHING / (float)(NUM_NEGS - 1))   // 0.1/31
#define TDSUM (TD0 + (float)NUM_NEGS * TDN)

__device__ __forceinline__ float dot8(const float4 a0, const float4 a1,
                                      const float4 b0, const float4 b1) {
    return a0.x * b0.x + a0.y * b0.y + a0.z * b0.z + a0.w * b0.w
         + a1.x * b1.x + a1.y * b1.y + a1.z * b1.z + a1.w * b1.w;
}

template <int COUNT>
__device__ __forceinline__ void dot_block(
    int first, int lane, int myrow,
    const float* __restrict__ s, const float* __restrict__ c,
    const float4 s0, const float4 s1,
    const int* colsh, const int* rowsh, float* dots)
{
    float sum[COUNT];
    #pragma unroll
    for (int k = 0; k < COUNT; ++k) {
        const float4* cp =
            reinterpret_cast<const float4*>(c + (size_t)colsh[first + k] * D);
        const float4 c0 = cp[lane];
        const float4 c1 = cp[lane + 64];
        float4 t0 = s0, t1 = s1;
        const int sr = rowsh[first + k];
        if (sr != myrow) {   // wave-uniform, never taken for these inputs
            const float4* spx =
                reinterpret_cast<const float4*>(s + (size_t)sr * D);
            t0 = spx[lane];
            t1 = spx[lane + 64];
        }
        sum[k] = dot8(c0, c1, t0, t1);
    }
    // Batched butterflies: COUNT independent 6-level reduces overlap in the
    // DS pipe instead of serializing per dot.
    #pragma unroll
    for (int k = 0; k < COUNT; ++k) {
        float v = sum[k];
        #pragma unroll
        for (int off = 32; off; off >>= 1) v += __shfl_down(v, off, 64);
        if (lane == 0) dots[first + k] = v;
    }
}

__global__ __launch_bounds__(256, 8) void ce_main_kernel(
    const float* __restrict__ s,              // (B, NM, D)
    const float* __restrict__ c,              // (B, NM, D)
    const int* __restrict__ pad,              // (B, N, M, M) bool as int32
    const int* __restrict__ valid,            // (B, NM, NM) bool as int32
    const int* __restrict__ inds,             // (B*NM*NUM_NEGS, 3)
    float4* __restrict__ partials)            // (NBQ) {ce*v, sim*v, v, 0}
{
    __shared__ float dots[NUM_NEGS + 1];
    __shared__ int   colsh[NUM_NEGS + 1];
    __shared__ int   rowsh[NUM_NEGS + 1];

    // XCD-batch affinity swizzle: XCD x owns batches {x, x+8}.
    const int p  = blockIdx.x;
    const int x  = p & 7;
    const int i  = p >> 3;
    const int b  = x + ((i >> 11) << 3);
    const int q  = i & (NM - 1);
    const int bq = b * NM + q;

    const int tid  = threadIdx.x;
    const int wave = tid >> 6;
    const int lane = tid & 63;
    const int myrow = bq;

    // Issue address-independent loads immediately.
    const float4* sp = reinterpret_cast<const float4*>(s + (size_t)myrow * D);
    const float4 s0 = sp[lane];
    const float4 s1 = sp[lane + 64];

    float4 d0 = make_float4(0.f, 0.f, 0.f, 0.f);
    float4 d1 = d0;
    float  padv = 0.0f;
    int bb = 0, rr = 0, cc = 0;
    if (wave == 0) {
        const float4* cp = reinterpret_cast<const float4*>(c + (size_t)myrow * D);
        d0 = cp[lane];
        d1 = cp[lane + 64];
        if (lane == 0) padv = pad[(size_t)bq * M] ? 0.0f : 1.0f;
        if (lane >= 1 && lane <= NUM_NEGS) {
            const size_t si = ((size_t)bq * NUM_NEGS + (lane - 1)) * 3;
            bb = inds[si + 0];
            rr = inds[si + 1];
            cc = inds[si + 2];
            colsh[lane] = bb * NM + cc;
            rowsh[lane] = bb * NM + rr;
        }
    }
    __syncthreads();

    // Wave 0: launch the random valid-gather NOW; it completes during the dot
    // phase and is consumed (from registers, lane k <-> dots[k]) after barrier 2.
    float vbit = 1.0f;
    if (wave == 0 && lane >= 1 && lane <= NUM_NEGS) {
        vbit = valid[((size_t)bb * NM + rr) * NM + cc] ? 1.0f : 0.0f;
    }

    if (wave == 0) {
        // Diagonal (data preloaded in d0/d1).
        float v = dot8(d0, d1, s0, s1);
        #pragma unroll
        for (int off = 32; off; off >>= 1) v += __shfl_down(v, off, 64);
        if (lane == 0) dots[0] = v;
        dot_block<5>(1, lane, myrow, s, c, s0, s1, colsh, rowsh, dots);
    } else if (wave == 1) {
        dot_block<9>(6, lane, myrow, s, c, s0, s1, colsh, rowsh, dots);
    } else if (wave == 2) {
        dot_block<9>(15, lane, myrow, s, c, s0, s1, colsh, rowsh, dots);
    } else {
        dot_block<9>(24, lane, myrow, s, c, s0, s1, colsh, rowsh, dots);
    }
    __syncthreads();

    // Wave-parallel epilogue.
    if (wave == 0) {
        float dj = (lane <= NUM_NEGS) ? dots[lane] : -INFINITY;
        if (lane >= 1 && lane <= NUM_NEGS) dj = (vbit != 0.0f) ? dj : 0.0f;
        float mx = dj;
        #pragma unroll
        for (int off = 32; off; off >>= 1) mx = fmaxf(mx, __shfl_xor(mx, off, 64));
        float e  = (lane <= NUM_NEGS) ? expf(dj - mx) : 0.0f;
        float sn = (lane >= 1 && lane <= NUM_NEGS) ? dj : 0.0f;
        #pragma unroll
        for (int off = 32; off; off >>= 1) {
            e  += __shfl_xor(e, off, 64);
            sn += __shfl_xor(sn, off, 64);
        }
        if (lane == 0) {
            const float num   = dj;                 // diagonal
            const float lse   = mx + logf(e);
            const float chunk = lse * TDSUM - (TD0 * num + TDN * sn);
            const float sim   = 1.0f - fminf(fmaxf(num, -1.0f), 1.0f);
            partials[bq] = make_float4(chunk * padv, sim * padv, padv, 0.0f);
        }
    }
}

// Stage 2: 64 blocks x 256 threads, grid-stride over NBQ, one partial per block.
__global__ __launch_bounds__(256) void reduce_kernel(
    const float4* __restrict__ partials, float4* __restrict__ blk)
{
    __shared__ float red[3][4];
    float a = 0.0f, bsum = 0.0f, cnt = 0.0f;
    for (int i = blockIdx.x * 256 + threadIdx.x; i < NBQ; i += 64 * 256) {
        float4 pr = partials[i];
        a += pr.x; bsum += pr.y; cnt += pr.z;
    }
    #pragma unroll
    for (int off = 32; off; off >>= 1) {
        a    += __shfl_down(a, off, 64);
        bsum += __shfl_down(bsum, off, 64);
        cnt  += __shfl_down(cnt, off, 64);
    }
    const int wave = threadIdx.x >> 6;
    const int lane = threadIdx.x & 63;
    if (lane == 0) { red[0][wave] = a; red[1][wave] = bsum; red[2][wave] = cnt; }
    __syncthreads();
    if (threadIdx.x == 0) {
        blk[blockIdx.x] = make_float4(red[0][0] + red[0][1] + red[0][2] + red[0][3],
                                      red[1][0] + red[1][1] + red[1][2] + red[1][3],
                                      red[2][0] + red[2][1] + red[2][2] + red[2][3],
                                      0.0f);
    }
}

// Stage 3: one wave sums 64 block partials and writes the two losses.
__global__ void finalize_kernel(const float4* __restrict__ blk,
                                float* __restrict__ out) {
    const int lane = threadIdx.x & 63;
    float4 pr = blk[lane];
    float a = pr.x, bsum = pr.y, cnt = pr.z;
    #pragma unroll
    for (int off = 32; off; off >>= 1) {
        a    += __shfl_down(a, off, 64);
        bsum += __shfl_down(bsum, off, 64);
        cnt  += __shfl_down(cnt, off, 64);
    }
    if (lane == 0) {
        out[0] = a / cnt;     // ce_loss
        out[1] = bsum / cnt;  // sim_loss
    }
}

extern "C" void kernel_launch(void* const* d_in, const int* in_sizes, int n_in,
                              void* d_out, int out_size, void* d_ws, size_t ws_size,
                              hipStream_t stream) {
    const float* s_ptr   = (const float*)d_in[0];
    const float* c_ptr   = (const float*)d_in[1];
    const int*   pad_ptr = (const int*)d_in[2];
    const int*   val_ptr = (const int*)d_in[3];
    const int*   ind_ptr = (const int*)d_in[4];
    float*       out_ptr = (float*)d_out;

    float4* partials = (float4*)d_ws;
    float4* blk      = (float4*)((char*)d_ws + (size_t)NBQ * sizeof(float4));

    ce_main_kernel<<<NBQ, 256, 0, stream>>>(s_ptr, c_ptr, pad_ptr, val_ptr,
                                            ind_ptr, partials);
    reduce_kernel<<<64, 256, 0, stream>>>(partials, blk);
    finalize_kernel<<<1, 64, 0, stream>>>(blk, out_ptr);
}

// Round 6
// 133.988 us; speedup vs baseline: 10.0773x; 10.0773x over previous
//
#include <hip/hip_runtime.h>
#include <math.h>

#define B 16
#define N 32
#define M 64
#define D 512
#define NM (N * M)          // 2048
#define NBQ (B * NM)        // 32768
#define NUM_NEGS 32
#define SMOOTHING 0.1f
#define TD0 (1.0f - SMOOTHING)                    // 0.9
#define TDN (SMOOTHING / (float)(NUM_NEGS - 1))   // 0.1/31
#define TDSUM (TD0 + (float)NUM_NEGS * TDN)

// ---------- bf16 helpers (manual, RNE) ----------
__device__ __forceinline__ unsigned int f2bf(float f) {
    unsigned int u = __float_as_uint(f);
    return (u + 0x7FFFu + ((u >> 16) & 1u)) >> 16;
}
// dot of 8 bf16 (packed in uint4) with 8 fp32 (two float4)
__device__ __forceinline__ float dot8_bf16(uint4 w, float4 s0, float4 s1) {
    float e0 = __uint_as_float(w.x << 16);
    float e1 = __uint_as_float(w.x & 0xFFFF0000u);
    float e2 = __uint_as_float(w.y << 16);
    float e3 = __uint_as_float(w.y & 0xFFFF0000u);
    float e4 = __uint_as_float(w.z << 16);
    float e5 = __uint_as_float(w.z & 0xFFFF0000u);
    float e6 = __uint_as_float(w.w << 16);
    float e7 = __uint_as_float(w.w & 0xFFFF0000u);
    return e0 * s0.x + e1 * s0.y + e2 * s0.z + e3 * s0.w
         + e4 * s1.x + e5 * s1.y + e6 * s1.z + e7 * s1.w;
}

// Streaming c -> bf16 (16,777,216 floats, 8 per thread, 8192 x 256 exact).
__global__ __launch_bounds__(256) void convert_c_kernel(
    const float* __restrict__ c, uint4* __restrict__ cb)
{
    const size_t i = (size_t)blockIdx.x * 256 + threadIdx.x;
    const float4* cp = reinterpret_cast<const float4*>(c);
    const float4 a = cp[2 * i];
    const float4 b4 = cp[2 * i + 1];
    uint4 w;
    w.x = f2bf(a.x)  | (f2bf(a.y)  << 16);
    w.y = f2bf(a.z)  | (f2bf(a.w)  << 16);
    w.z = f2bf(b4.x) | (f2bf(b4.y) << 16);
    w.w = f2bf(b4.z) | (f2bf(b4.w) << 16);
    cb[i] = w;
}

// ---------- main kernel: round-4 skeleton, bf16 c-gather ----------
__global__ __launch_bounds__(256) void ce_main_bf16_kernel(
    const float* __restrict__ s,              // (B, NM, D) fp32
    const uint4* __restrict__ cb,             // (B*NM, D/8) bf16-packed rows
    const int* __restrict__ pad,
    const int* __restrict__ valid,
    const int* __restrict__ inds,
    float4* __restrict__ partials)
{
    __shared__ float dots[NUM_NEGS + 1];
    __shared__ int   colsh[NUM_NEGS + 1];
    __shared__ int   rowsh[NUM_NEGS + 1];
    __shared__ unsigned char vmsk[NUM_NEGS + 1];

    // XCD-batch affinity swizzle: XCD x owns batches {x, x+8}.
    const int p  = blockIdx.x;
    const int x  = p & 7;
    const int i  = p >> 3;
    const int b  = x + ((i >> 11) << 3);
    const int q  = i & (NM - 1);
    const int bq = b * NM + q;

    const int tid  = threadIdx.x;
    const int wave = tid >> 6;
    const int lane = tid & 63;
    const int myrow = bq;

    // Compact setup phase (proven in round 4): indices + valid gather.
    if (tid < NUM_NEGS + 1) {
        int col, srow, vb;
        if (tid == 0) {
            col = bq; srow = bq; vb = 1;
        } else {
            size_t si = ((size_t)bq * NUM_NEGS + (tid - 1)) * 3;
            int bb = inds[si + 0];
            int rr = inds[si + 1];
            int cc = inds[si + 2];
            col  = bb * NM + cc;
            srow = bb * NM + rr;
            vb   = valid[((size_t)bb * NM + rr) * NM + cc] ? 1 : 0;
        }
        colsh[tid] = col;
        rowsh[tid] = srow;
        vmsk[tid]  = (unsigned char)vb;
    }
    __syncthreads();

    // s-row in registers: lane owns elements 8*lane .. 8*lane+7.
    const float4* sp = reinterpret_cast<const float4*>(s + (size_t)myrow * D);
    const float4 s0 = sp[2 * lane];
    const float4 s1 = sp[2 * lane + 1];

    // 4 pair-iterations: wave w handles dots {w, w+4, ..., w+28} (MLP = 2).
    #pragma unroll
    for (int jj = 0; jj < 4; ++jj) {
        const int j0 = wave + jj * 8;
        const int j1 = j0 + 4;
        uint4 w0 = cb[(size_t)colsh[j0] * (D / 8) + lane];
        uint4 w1 = cb[(size_t)colsh[j1] * (D / 8) + lane];
        float4 t00 = s0, t01 = s1, t10 = s0, t11 = s1;
        if (rowsh[j0] != myrow) {   // wave-uniform, never taken for these inputs
            const float4* spx = reinterpret_cast<const float4*>(s + (size_t)rowsh[j0] * D);
            t00 = spx[2 * lane]; t01 = spx[2 * lane + 1];
        }
        if (rowsh[j1] != myrow) {
            const float4* spx = reinterpret_cast<const float4*>(s + (size_t)rowsh[j1] * D);
            t10 = spx[2 * lane]; t11 = spx[2 * lane + 1];
        }
        float sum0 = dot8_bf16(w0, t00, t01);
        float sum1 = dot8_bf16(w1, t10, t11);
        #pragma unroll
        for (int off = 32; off; off >>= 1) {
            sum0 += __shfl_down(sum0, off, 64);
            sum1 += __shfl_down(sum1, off, 64);
        }
        if (lane == 0) {
            dots[j0] = vmsk[j0] ? sum0 : 0.0f;
            dots[j1] = vmsk[j1] ? sum1 : 0.0f;
        }
    }
    if (wave == 0) {   // dot 32
        uint4 w0 = cb[(size_t)colsh[32] * (D / 8) + lane];
        float4 t0 = s0, t1 = s1;
        if (rowsh[32] != myrow) {
            const float4* spx = reinterpret_cast<const float4*>(s + (size_t)rowsh[32] * D);
            t0 = spx[2 * lane]; t1 = spx[2 * lane + 1];
        }
        float sum = dot8_bf16(w0, t0, t1);
        #pragma unroll
        for (int off = 32; off; off >>= 1) sum += __shfl_down(sum, off, 64);
        if (lane == 0) dots[32] = vmsk[32] ? sum : 0.0f;
    }
    __syncthreads();

    // Wave-parallel epilogue.
    if (wave == 0) {
        const float dj = (lane <= NUM_NEGS) ? dots[lane] : -INFINITY;
        float mx = dj;
        #pragma unroll
        for (int off = 32; off; off >>= 1) mx = fmaxf(mx, __shfl_xor(mx, off, 64));
        float e  = (lane <= NUM_NEGS) ? expf(dj - mx) : 0.0f;
        float sn = (lane >= 1 && lane <= NUM_NEGS) ? dj : 0.0f;
        #pragma unroll
        for (int off = 32; off; off >>= 1) {
            e  += __shfl_xor(e, off, 64);
            sn += __shfl_xor(sn, off, 64);
        }
        if (lane == 0) {
            const float num   = dj;             // dots[0]
            const float lse   = mx + logf(e);
            const float chunk = lse * TDSUM - (TD0 * num + TDN * sn);
            const float v     = pad[(size_t)bq * M] ? 0.0f : 1.0f;
            const float sim   = 1.0f - fminf(fmaxf(num, -1.0f), 1.0f);
            partials[bq] = make_float4(chunk * v, sim * v, v, 0.0f);
        }
    }
}

// ---------- fallback: round-4 fp32 kernel (used if ws too small) ----------
__global__ __launch_bounds__(256) void ce_main_fp32_kernel(
    const float* __restrict__ s, const float* __restrict__ c,
    const int* __restrict__ pad, const int* __restrict__ valid,
    const int* __restrict__ inds, float4* __restrict__ partials)
{
    __shared__ float dots[NUM_NEGS + 1];
    __shared__ int   colsh[NUM_NEGS + 1];
    __shared__ int   rowsh[NUM_NEGS + 1];
    __shared__ unsigned char vmsk[NUM_NEGS + 1];

    const int p  = blockIdx.x;
    const int x  = p & 7;
    const int i  = p >> 3;
    const int b  = x + ((i >> 11) << 3);
    const int q  = i & (NM - 1);
    const int bq = b * NM + q;

    const int tid  = threadIdx.x;
    const int wave = tid >> 6;
    const int lane = tid & 63;

    if (tid < NUM_NEGS + 1) {
        int col, srow, vb;
        if (tid == 0) { col = bq; srow = bq; vb = 1; }
        else {
            size_t si = ((size_t)bq * NUM_NEGS + (tid - 1)) * 3;
            int bb = inds[si + 0]; int rr = inds[si + 1]; int cc = inds[si + 2];
            col = bb * NM + cc; srow = bb * NM + rr;
            vb  = valid[((size_t)bb * NM + rr) * NM + cc] ? 1 : 0;
        }
        colsh[tid] = col; rowsh[tid] = srow; vmsk[tid] = (unsigned char)vb;
    }
    __syncthreads();

    const int myrow = bq;
    const float4* sp = reinterpret_cast<const float4*>(s + (size_t)myrow * D);
    const float4 s0 = sp[lane];
    const float4 s1 = sp[lane + 64];

    for (int j = wave; j < NUM_NEGS + 1; j += 4) {
        const float4* cp = reinterpret_cast<const float4*>(c + (size_t)colsh[j] * D);
        float4 c0 = cp[lane];
        float4 c1 = cp[lane + 64];
        float4 t0 = s0, t1 = s1;
        if (rowsh[j] != myrow) {
            const float4* spx = reinterpret_cast<const float4*>(s + (size_t)rowsh[j] * D);
            t0 = spx[lane]; t1 = spx[lane + 64];
        }
        float sum = c0.x * t0.x + c0.y * t0.y + c0.z * t0.z + c0.w * t0.w
                  + c1.x * t1.x + c1.y * t1.y + c1.z * t1.z + c1.w * t1.w;
        #pragma unroll
        for (int off = 32; off; off >>= 1) sum += __shfl_down(sum, off, 64);
        if (lane == 0) dots[j] = vmsk[j] ? sum : 0.0f;
    }
    __syncthreads();

    if (wave == 0) {
        const float dj = (lane <= NUM_NEGS) ? dots[lane] : -INFINITY;
        float mx = dj;
        #pragma unroll
        for (int off = 32; off; off >>= 1) mx = fmaxf(mx, __shfl_xor(mx, off, 64));
        float e  = (lane <= NUM_NEGS) ? expf(dj - mx) : 0.0f;
        float sn = (lane >= 1 && lane <= NUM_NEGS) ? dj : 0.0f;
        #pragma unroll
        for (int off = 32; off; off >>= 1) { e += __shfl_xor(e, off, 64); sn += __shfl_xor(sn, off, 64); }
        if (lane == 0) {
            const float num   = dj;
            const float lse   = mx + logf(e);
            const float chunk = lse * TDSUM - (TD0 * num + TDN * sn);
            const float v     = pad[(size_t)bq * M] ? 0.0f : 1.0f;
            const float sim   = 1.0f - fminf(fmaxf(num, -1.0f), 1.0f);
            partials[bq] = make_float4(chunk * v, sim * v, v, 0.0f);
        }
    }
}

// Stage 2: 64 blocks x 256 threads, grid-stride over NBQ, one partial per block.
__global__ __launch_bounds__(256) void reduce_kernel(
    const float4* __restrict__ partials, float4* __restrict__ blk)
{
    __shared__ float red[3][4];
    float a = 0.0f, bsum = 0.0f, cnt = 0.0f;
    for (int i = blockIdx.x * 256 + threadIdx.x; i < NBQ; i += 64 * 256) {
        float4 pr = partials[i];
        a += pr.x; bsum += pr.y; cnt += pr.z;
    }
    #pragma unroll
    for (int off = 32; off; off >>= 1) {
        a    += __shfl_down(a, off, 64);
        bsum += __shfl_down(bsum, off, 64);
        cnt  += __shfl_down(cnt, off, 64);
    }
    const int wave = threadIdx.x >> 6;
    const int lane = threadIdx.x & 63;
    if (lane == 0) { red[0][wave] = a; red[1][wave] = bsum; red[2][wave] = cnt; }
    __syncthreads();
    if (threadIdx.x == 0) {
        blk[blockIdx.x] = make_float4(red[0][0] + red[0][1] + red[0][2] + red[0][3],
                                      red[1][0] + red[1][1] + red[1][2] + red[1][3],
                                      red[2][0] + red[2][1] + red[2][2] + red[2][3],
                                      0.0f);
    }
}

__global__ void finalize_kernel(const float4* __restrict__ blk,
                                float* __restrict__ out) {
    const int lane = threadIdx.x & 63;
    float4 pr = blk[lane];
    float a = pr.x, bsum = pr.y, cnt = pr.z;
    #pragma unroll
    for (int off = 32; off; off >>= 1) {
        a    += __shfl_down(a, off, 64);
        bsum += __shfl_down(bsum, off, 64);
        cnt  += __shfl_down(cnt, off, 64);
    }
    if (lane == 0) {
        out[0] = a / cnt;     // ce_loss
        out[1] = bsum / cnt;  // sim_loss
    }
}

extern "C" void kernel_launch(void* const* d_in, const int* in_sizes, int n_in,
                              void* d_out, int out_size, void* d_ws, size_t ws_size,
                              hipStream_t stream) {
    const float* s_ptr   = (const float*)d_in[0];
    const float* c_ptr   = (const float*)d_in[1];
    const int*   pad_ptr = (const int*)d_in[2];
    const int*   val_ptr = (const int*)d_in[3];
    const int*   ind_ptr = (const int*)d_in[4];
    float*       out_ptr = (float*)d_out;

    // ws layout: [0, 512K) partials; [512K, 512K+1K) blk; [1M, 1M+32M) c_bf16
    float4* partials = (float4*)d_ws;
    float4* blk      = (float4*)((char*)d_ws + (size_t)NBQ * sizeof(float4));
    uint4*  cb       = (uint4*)((char*)d_ws + (1u << 20));
    const size_t need = (1u << 20) + (size_t)B * NM * D * 2;

    if (ws_size >= need) {
        convert_c_kernel<<<8192, 256, 0, stream>>>(c_ptr, cb);
        ce_main_bf16_kernel<<<NBQ, 256, 0, stream>>>(s_ptr, cb, pad_ptr, val_ptr,
                                                     ind_ptr, partials);
    } else {
        ce_main_fp32_kernel<<<NBQ, 256, 0, stream>>>(s_ptr, c_ptr, pad_ptr, val_ptr,
                                                     ind_ptr, partials);
    }
    reduce_kernel<<<64, 256, 0, stream>>>(partials, blk);
    finalize_kernel<<<1, 64, 0, stream>>>(blk, out_ptr);
}